// Round 14
// baseline (283.984 us; speedup 1.0000x reference)
//
#include <hip/hip_runtime.h>

#define NROWS 16384
#define KCODES 8192
#define DDIM 256
#define MARGIN 2.0f
#define SEG 192
#define NCT 16     // 256-col tiles per block (block sweeps 4096 cols)
#define GATHER_BLOCKS (NROWS / 16)

typedef __attribute__((ext_vector_type(8))) short short8;
typedef __attribute__((ext_vector_type(4))) float f32x4;

// ---------------- helpers ----------------
__device__ inline unsigned short f2bf(float x) {
    unsigned u = __float_as_uint(x);
    return (unsigned short)((u + 0x7FFFu + ((u >> 16) & 1u)) >> 16);  // RNE
}

__device__ inline void gload16(const void* g, void* l) {
    __builtin_amdgcn_global_load_lds(
        (const __attribute__((address_space(1))) unsigned char*)g,
        (__attribute__((address_space(3))) unsigned char*)l, 16, 0, 0);
}

__device__ inline unsigned mbcnt64(unsigned long long m) {
    unsigned lo = __builtin_amdgcn_mbcnt_lo((unsigned)m, 0u);
    return __builtin_amdgcn_mbcnt_hi((unsigned)(m >> 32), lo);
}

__device__ inline void exact_rescore(const float* __restrict__ z, const float* __restrict__ cb,
                                     const float* __restrict__ z2g, const float* __restrict__ e2g,
                                     int grow, int gcol, unsigned long long* best) {
    const float4* av = reinterpret_cast<const float4*>(z + (size_t)grow * DDIM);
    const float4* bv = reinterpret_cast<const float4*>(cb + (size_t)gcol * DDIM);
    float dot = 0.f;
    #pragma unroll 8
    for (int j = 0; j < 64; ++j) {
        const float4 xa = av[j], xb = bv[j];
        dot = fmaf(xa.x, xb.x, fmaf(xa.y, xb.y, fmaf(xa.z, xb.z, fmaf(xa.w, xb.w, dot))));
    }
    const float de = z2g[grow] + e2g[gcol] - 2.0f * dot;
    const unsigned long long key =
        ((unsigned long long)__float_as_uint(de) << 32) | (unsigned)gcol;
    atomicMin(best + grow, key);
}

// ---------------- convert fp32 -> bf16 pre-tiled fragment layout + fused sumsq ----------------
// chunk (g, kb2): 1 KB, slot s: row g*16 + (s&15), k = kb2*32 + (s>>4)*8 .. +8
__global__ __launch_bounds__(256) void k_convert(
    const float* __restrict__ z, unsigned short* __restrict__ z_t,
    const float* __restrict__ cb, unsigned short* __restrict__ cb_t,
    float* __restrict__ z2, float* __restrict__ e2,
    unsigned long long* best, float* accum, unsigned* counters, unsigned* gctr)
{
    const int tid = threadIdx.x;
    const int bx = blockIdx.x;
    if (bx < 64) {
        const int gid = bx * 256 + tid;
        best[gid] = 0xFFFFFFFFFFFFFFFFull;
    }
    if (bx == 0) {
        if (tid < 16) counters[tid * 16] = 0u;
        if (tid == 0) { accum[0] = 0.0f; gctr[0] = 0u; }
    }
    const float* in;
    unsigned short* outt;
    float* sumsq;
    int g;
    if (bx < 256) { in = z;  outt = z_t;  sumsq = z2; g = bx * 4 + (tid >> 6); }
    else          { in = cb; outt = cb_t; sumsq = e2; g = (bx - 256) * 4 + (tid >> 6); }
    const int lane = tid & 63;
    const int row = g * 16 + (lane & 15);
    const int ko = (lane >> 4) * 8;
    float ss = 0.f;
    #pragma unroll
    for (int kb2 = 0; kb2 < 8; ++kb2) {
        const float4* src = reinterpret_cast<const float4*>(in + (size_t)row * DDIM + kb2 * 32 + ko);
        const float4 a = src[0], b = src[1];
        ss += a.x * a.x + a.y * a.y + a.z * a.z + a.w * a.w
            + b.x * b.x + b.y * b.y + b.z * b.z + b.w * b.w;
        short8 p;
        p[0] = (short)f2bf(a.x); p[1] = (short)f2bf(a.y); p[2] = (short)f2bf(a.z); p[3] = (short)f2bf(a.w);
        p[4] = (short)f2bf(b.x); p[5] = (short)f2bf(b.y); p[6] = (short)f2bf(b.z); p[7] = (short)f2bf(b.w);
        *reinterpret_cast<short8*>(outt + (((size_t)(g * 8 + kb2)) << 9) + lane * 8) = p;
    }
    ss += __shfl_xor(ss, 16);
    ss += __shfl_xor(ss, 32);
    if (lane < 16) sumsq[g * 16 + lane] = ss;
}

// ---------------- MFMA screen: 64 rows x 4096 cols, wave-tile 64x64, 2 blocks/CU ----------------
// Single sweep; per-row running min; emit d <= min(wave-run, block-run-prev)+MARGIN.
// Block-min merge hidden in kb2==1 slot of next tile (ordered by K-loop barriers).
// LDS: A 32K @0 | B dbuf 2x16K @32768 | rowmin[4][64] @65536 | thrbuf[64] @66560 | wl 4xSEG @66816
__global__ __launch_bounds__(256, 2) void k_screen(
    const float* __restrict__ z, const float* __restrict__ cbp,
    const unsigned short* __restrict__ z_t, const unsigned short* __restrict__ cb_t,
    const float* __restrict__ z2g, const float* __restrict__ e2g,
    unsigned long long* __restrict__ best,
    unsigned* __restrict__ counters, unsigned* __restrict__ list, unsigned C16)
{
    __shared__ __align__(16) char smem[69888];
    char* ldsA = smem;                          // 64 rows x 256 K, 32 chunks
    char* ldsB = smem + 32768;                  // dbuf 2 x (256 cols x 32 K)
    float* rowmin = (float*)(smem + 65536);     // [4][64] per-wave running row min
    float* thrbuf = (float*)(smem + 66560);     // [64] block running min (tiles 0..ci-1)
    unsigned* wl_all = (unsigned*)(smem + 66816);

    const int tid = threadIdx.x;
    const int lane = tid & 63;
    const int wave = tid >> 6;     // 0..3 = wn (64-col group); wave covers all 64 rows
    const int lhi = lane >> 4;
    const int llo = lane & 15;

    const int bx = blockIdx.x;     // 512 blocks = 256 row-bands x 2 cgrp
    const int rt = bx & 255;       // 64-row band
    const int cgrp = bx >> 8;      // 0..1
    const int row0 = rt * 64;
    const int colbase = cgrp * 4096;

    // ---- prologue: stage A band (32 KB = 32 chunks) + first B + init ----
    #pragma unroll
    for (int i = 0; i < 8; ++i) {
        const int c = wave * 8 + i;            // gl = c>>3 (0..3), kb2 = c&7
        gload16((const char*)z_t + (((size_t)((rt * 4 + (c >> 3)) * 8 + (c & 7))) << 10) + lane * 16,
                ldsA + c * 1024);
    }
    auto STAGE_B = [&](int b, int ci_, int kb2_) {
        #pragma unroll
        for (int i = 0; i < 4; ++i) {
            const int c = wave * 4 + i;        // local col-16-group 0..15
            const int gb = cgrp * 256 + ci_ * 16 + c;
            gload16((const char*)cb_t + (((size_t)(gb * 8 + kb2_)) << 10) + lane * 16,
                    ldsB + b * 16384 + c * 1024);
        }
    };
    STAGE_B(0, 0, 0);
    if (tid < 64) thrbuf[tid] = 3.0e38f;
    __syncthreads();

    unsigned* wl = wl_all + wave * SEG;
    float rm[4][4];
    #pragma unroll
    for (int fm = 0; fm < 4; ++fm)
        #pragma unroll
        for (int rg = 0; rg < 4; ++rg) rm[fm][rg] = 3.0e38f;

    #pragma unroll 1
    for (int ci = 0; ci < NCT; ++ci) {
        f32x4 acc[4][4];
        #pragma unroll
        for (int i = 0; i < 4; ++i)
            #pragma unroll
            for (int j = 0; j < 4; ++j) { acc[i][j][0]=0.f; acc[i][j][1]=0.f; acc[i][j][2]=0.f; acc[i][j][3]=0.f; }

        // ---- K loop: 8 steps of K=32, 2-phase dbuf, 1 barrier/step ----
        #pragma unroll
        for (int kb2 = 0; kb2 < 8; ++kb2) {
            const int pb = kb2 & 1;
            if (kb2 < 7) STAGE_B(pb ^ 1, ci, kb2 + 1);
            else if (ci < NCT - 1) STAGE_B(pb ^ 1, ci + 1, 0);

            // block-min merge over tiles 0..ci-1 (ordered by kb2=0's barrier)
            if (kb2 == 1 && ci > 0 && tid < 64) {
                float a = fminf(fminf(rowmin[tid], rowmin[64 + tid]),
                                fminf(rowmin[128 + tid], rowmin[192 + tid]));
                thrbuf[tid] = fminf(thrbuf[tid], a);
            }

            char* bufB = ldsB + pb * 16384;
            short8 bfr[4];
            #pragma unroll
            for (int fn = 0; fn < 4; ++fn)
                bfr[fn] = *reinterpret_cast<const short8*>(bufB + (wave * 4 + fn) * 1024 + lane * 16);
            #pragma unroll
            for (int fm = 0; fm < 4; ++fm) {
                const short8 af = *reinterpret_cast<const short8*>(
                    ldsA + ((fm * 8) + kb2) * 1024 + lane * 16);
                #pragma unroll
                for (int fn = 0; fn < 4; ++fn)
                    acc[fm][fn] = __builtin_amdgcn_mfma_f32_16x16x32_bf16(af, bfr[fn], acc[fm][fn], 0, 0, 0);
            }
            __syncthreads();
        }

        // ---- barrier-free epilogue: min update + emission ----
        const int c0 = colbase + ci * 256 + wave * 64 + llo;
        float e2c[4];
        #pragma unroll
        for (int fn = 0; fn < 4; ++fn) e2c[fn] = e2g[c0 + fn * 16];

        unsigned wcount = 0;
        #pragma unroll
        for (int fm = 0; fm < 4; ++fm) {
            #pragma unroll
            for (int rg = 0; rg < 4; ++rg) {
                const int rl = fm * 16 + lhi * 4 + rg;
                float d[4];
                #pragma unroll
                for (int fn = 0; fn < 4; ++fn) d[fn] = fmaf(-2.0f, acc[fm][fn][rg], e2c[fn]);
                float m = fminf(fminf(d[0], d[1]), fminf(d[2], d[3]));
                #pragma unroll
                for (int off = 1; off < 16; off <<= 1) m = fminf(m, __shfl_xor(m, off));
                const float rmv = fminf(rm[fm][rg], m);
                rm[fm][rg] = rmv;
                if (llo == 0) rowmin[wave * 64 + rl] = rmv;
                const float thr = fminf(rmv, thrbuf[rl]) + MARGIN;
                const bool hit = (d[0] <= thr) | (d[1] <= thr) | (d[2] <= thr) | (d[3] <= thr);
                if (__any(hit)) {
                    const int grow = row0 + rl;
                    #pragma unroll
                    for (int fn = 0; fn < 4; ++fn) {
                        const bool p = d[fn] <= thr;
                        const unsigned long long mask = __ballot(p);
                        if (mask) {
                            if (p) {
                                const unsigned pos = wcount + mbcnt64(mask);
                                const unsigned v = ((unsigned)grow << 13) | (unsigned)(c0 + fn * 16);
                                if (pos < SEG) wl[pos] = v;
                                else exact_rescore(z, cbp, z2g, e2g, grow, c0 + fn * 16, best);
                            }
                            wcount += (unsigned)__popcll(mask);
                        }
                    }
                }
            }
        }

        // per-tile flush: one atomic per wave to a spread shard
        const unsigned n = wcount < SEG ? wcount : SEG;
        const int sh = ((bx & 3) * 4 + wave);
        unsigned base = 0;
        if (lane == 0 && n) base = atomicAdd(&counters[sh * 16], n);
        base = (unsigned)__shfl((int)base, 0);
        for (unsigned i = lane; i < n; i += 64) {
            const unsigned v = wl[i];
            const unsigned slot = base + i;
            if (slot < C16) list[(size_t)sh * C16 + slot] = v;
            else exact_rescore(z, cbp, z2g, e2g, (int)(v >> 13), (int)(v & 8191u), best);
        }
    }
}

// ---------------- exact rescore of sharded candidate lists (wave per candidate) ----------------
__global__ __launch_bounds__(256) void k_rescore(
    const float* __restrict__ z, const float* __restrict__ cbp,
    const float* __restrict__ z2g, const float* __restrict__ e2g,
    const unsigned* __restrict__ list, const unsigned* __restrict__ counters, unsigned C16,
    unsigned long long* best)
{
    const unsigned wid = (blockIdx.x * blockDim.x + threadIdx.x) >> 6;
    const unsigned nw = (gridDim.x * blockDim.x) >> 6;
    const int lane = threadIdx.x & 63;
    #pragma unroll 1
    for (int s = 0; s < 16; ++s) {
        const unsigned n = min(counters[s * 16], C16);
        const unsigned* shard = list + (size_t)s * C16;
        for (unsigned i = wid; i < n; i += nw) {
            const unsigned v = shard[i];
            const unsigned row = v >> 13, col = v & 8191u;
            const float4 a = *reinterpret_cast<const float4*>(z + (size_t)row * DDIM + lane * 4);
            const float4 b = *reinterpret_cast<const float4*>(cbp + (size_t)col * DDIM + lane * 4);
            float sdot = fmaf(a.x, b.x, fmaf(a.y, b.y, fmaf(a.z, b.z, a.w * b.w)));
            #pragma unroll
            for (int off = 1; off < 64; off <<= 1) sdot += __shfl_xor(sdot, off);
            if (lane == 0) {
                const float de = z2g[row] + e2g[col] - 2.0f * sdot;
                const unsigned long long key =
                    ((unsigned long long)__float_as_uint(de) << 32) | col;
                atomicMin(&best[row], key);
            }
        }
    }
}

// ---------------- gather + z_st + loss + final scalars (ticket) ----------------
__global__ __launch_bounds__(1024) void k_gather(
    const float* __restrict__ z, const float* __restrict__ cbp,
    const unsigned long long* __restrict__ best,
    float* __restrict__ out, float* __restrict__ accum, unsigned* __restrict__ gctr)
{
    __shared__ float wsum[16];
    const int tid = threadIdx.x;
    const int row = blockIdx.x * 16 + (tid >> 6);
    const int lane = tid & 63;
    const unsigned k = (unsigned)(best[row] & 0xFFFFFFFFull);
    const float4 ze = *reinterpret_cast<const float4*>(z + (size_t)row * DDIM + lane * 4);
    const float4 cq = *reinterpret_cast<const float4*>(cbp + (size_t)k * DDIM + lane * 4);
    float4 zst;
    zst.x = ze.x + (cq.x - ze.x); zst.y = ze.y + (cq.y - ze.y);
    zst.z = ze.z + (cq.z - ze.z); zst.w = ze.w + (cq.w - ze.w);
    *reinterpret_cast<float4*>(out + (size_t)row * DDIM + lane * 4) = zst;
    const float dx = cq.x - ze.x, dy = cq.y - ze.y, dz = cq.z - ze.z, dw = cq.w - ze.w;
    float s = dx * dx + dy * dy + dz * dz + dw * dw;
    #pragma unroll
    for (int off = 32; off > 0; off >>= 1) s += __shfl_down(s, off);
    if (lane == 0) {
        wsum[tid >> 6] = s;
        out[(size_t)NROWS * DDIM + row] = (float)k;
    }
    __syncthreads();
    if (tid == 0) {
        float tot = 0.f;
        #pragma unroll
        for (int i = 0; i < 16; ++i) tot += wsum[i];
        atomicAdd(accum, tot);
        __threadfence();
        const unsigned t = atomicAdd(gctr, 1u);
        if (t == GATHER_BLOCKS - 1) {
            const float total = atomicAdd(accum, 0.0f);
            const float m = total / (float)(NROWS * DDIM);
            out[(size_t)NROWS * DDIM + NROWS + 0] = m;
            out[(size_t)NROWS * DDIM + NROWS + 1] = m;
        }
    }
}

extern "C" void kernel_launch(void* const* d_in, const int* in_sizes, int n_in,
                              void* d_out, int out_size, void* d_ws, size_t ws_size,
                              hipStream_t stream)
{
    const float* z  = (const float*)d_in[0];
    const float* cb = (const float*)d_in[1];
    float* out = (float*)d_out;

    // bf16 pre-tiled scratch lives in d_out's z_st region (12 MB of 16.8 MB),
    // consumed by k_screen/k_rescore and fully overwritten afterwards by k_gather.
    unsigned short* z_t  = (unsigned short*)d_out;                      // 8 MB
    unsigned short* cb_t = (unsigned short*)((char*)d_out + 8388608);   // 4 MB

    char* ws = (char*)d_ws;
    unsigned long long* best = (unsigned long long*)ws;   // 131072 B
    float* e2      = (float*)(ws + 131072);               // 32768 B
    float* z2      = (float*)(ws + 163840);               // 65536 B
    float* accum   = (float*)(ws + 229376);
    unsigned* gctr = (unsigned*)(ws + 229380);
    unsigned* counters = (unsigned*)(ws + 229440);        // 16 shard counters, 64B apart
    unsigned* list = (unsigned*)(ws + 230464);
    unsigned C16 = 0;
    if (ws_size > 230464 + 64) {
        size_t c = (ws_size - 230464) / 4 / 16;
        if (c > (1u << 19)) c = (1u << 19);
        C16 = (unsigned)c;
    }

    k_convert<<<384, 256, 0, stream>>>(z, z_t, cb, cb_t, z2, e2, best, accum, counters, gctr);
    k_screen<<<512, 256, 0, stream>>>(z, cb, z_t, cb_t, z2, e2, best, counters, list, C16);
    k_rescore<<<2048, 256, 0, stream>>>(z, cb, z2, e2, list, counters, C16, best);
    k_gather<<<GATHER_BLOCKS, 1024, 0, stream>>>(z, cb, best, out, accum, gctr);
}

// Round 15
// 249.700 us; speedup vs baseline: 1.1373x; 1.1373x over previous
//
#include <hip/hip_runtime.h>

#define NROWS 16384
#define KCODES 8192
#define DDIM 256
#define MARGIN 2.0f
#define SEG 192
#define NCT 16     // 512-col tiles (block sweeps all 8192 cols)
#define GATHER_BLOCKS (NROWS / 16)

typedef __attribute__((ext_vector_type(8))) short short8;
typedef __attribute__((ext_vector_type(4))) float f32x4;

// ---------------- helpers ----------------
__device__ inline unsigned short f2bf(float x) {
    unsigned u = __float_as_uint(x);
    return (unsigned short)((u + 0x7FFFu + ((u >> 16) & 1u)) >> 16);  // RNE
}

__device__ inline void gload16(const void* g, void* l) {
    __builtin_amdgcn_global_load_lds(
        (const __attribute__((address_space(1))) unsigned char*)g,
        (__attribute__((address_space(3))) unsigned char*)l, 16, 0, 0);
}

__device__ inline unsigned mbcnt64(unsigned long long m) {
    unsigned lo = __builtin_amdgcn_mbcnt_lo((unsigned)m, 0u);
    return __builtin_amdgcn_mbcnt_hi((unsigned)(m >> 32), lo);
}

__device__ inline void exact_rescore(const float* __restrict__ z, const float* __restrict__ cb,
                                     const float* __restrict__ z2g, const float* __restrict__ e2g,
                                     int grow, int gcol, unsigned long long* best) {
    const float4* av = reinterpret_cast<const float4*>(z + (size_t)grow * DDIM);
    const float4* bv = reinterpret_cast<const float4*>(cb + (size_t)gcol * DDIM);
    float dot = 0.f;
    #pragma unroll 8
    for (int j = 0; j < 64; ++j) {
        const float4 xa = av[j], xb = bv[j];
        dot = fmaf(xa.x, xb.x, fmaf(xa.y, xb.y, fmaf(xa.z, xb.z, fmaf(xa.w, xb.w, dot))));
    }
    const float de = z2g[grow] + e2g[gcol] - 2.0f * dot;
    const unsigned long long key =
        ((unsigned long long)__float_as_uint(de) << 32) | (unsigned)gcol;
    atomicMin(best + grow, key);
}

// ---------------- convert fp32 -> bf16 pre-tiled fragment layout + fused sumsq ----------------
__global__ __launch_bounds__(256) void k_convert(
    const float* __restrict__ z, unsigned short* __restrict__ z_t,
    const float* __restrict__ cb, unsigned short* __restrict__ cb_t,
    float* __restrict__ z2, float* __restrict__ e2,
    unsigned long long* best, float* accum, unsigned* counters, unsigned* gctr)
{
    const int tid = threadIdx.x;
    const int bx = blockIdx.x;
    if (bx < 64) {
        const int gid = bx * 256 + tid;
        best[gid] = 0xFFFFFFFFFFFFFFFFull;
    }
    if (bx == 0) {
        if (tid < 16) counters[tid * 16] = 0u;
        if (tid == 0) { accum[0] = 0.0f; gctr[0] = 0u; }
    }
    const float* in;
    unsigned short* outt;
    float* sumsq;
    int g;
    if (bx < 256) { in = z;  outt = z_t;  sumsq = z2; g = bx * 4 + (tid >> 6); }
    else          { in = cb; outt = cb_t; sumsq = e2; g = (bx - 256) * 4 + (tid >> 6); }
    const int lane = tid & 63;
    const int row = g * 16 + (lane & 15);
    const int ko = (lane >> 4) * 8;
    float ss = 0.f;
    #pragma unroll
    for (int kb2 = 0; kb2 < 8; ++kb2) {
        const float4* src = reinterpret_cast<const float4*>(in + (size_t)row * DDIM + kb2 * 32 + ko);
        const float4 a = src[0], b = src[1];
        ss += a.x * a.x + a.y * a.y + a.z * a.z + a.w * a.w
            + b.x * b.x + b.y * b.y + b.z * b.z + b.w * b.w;
        short8 p;
        p[0] = (short)f2bf(a.x); p[1] = (short)f2bf(a.y); p[2] = (short)f2bf(a.z); p[3] = (short)f2bf(a.w);
        p[4] = (short)f2bf(b.x); p[5] = (short)f2bf(b.y); p[6] = (short)f2bf(b.z); p[7] = (short)f2bf(b.w);
        *reinterpret_cast<short8*>(outt + (((size_t)(g * 8 + kb2)) << 9) + lane * 8) = p;
    }
    ss += __shfl_xor(ss, 16);
    ss += __shfl_xor(ss, 32);
    if (lane < 16) sumsq[g * 16 + lane] = ss;
}

// ---------------- MFMA screen: r13 geometry + counted-vmcnt triple-buffer K-loop ----------------
// 64 rows x ALL 8192 cols per block; wave tile 32x64 (acc[2][4], no-spill). Single sweep;
// emit d <= min(wave-run, block-run-prev)+MARGIN; block-min merge in kb2==1 slot.
// Sync: raw s_barrier + s_waitcnt vmcnt(2) -- this step's 2 stage-loads stay in flight.
// LDS: A 32K @0 | B 3x32K @32768 | rowmin[8][64] @131072 | thrbuf[64] @133120 | wl 16xSEG @133376
__global__ __launch_bounds__(1024, 4) void k_screen(
    const float* __restrict__ z, const float* __restrict__ cbp,
    const unsigned short* __restrict__ z_t, const unsigned short* __restrict__ cb_t,
    const float* __restrict__ z2g, const float* __restrict__ e2g,
    unsigned long long* __restrict__ best,
    unsigned* __restrict__ counters, unsigned* __restrict__ list, unsigned C16)
{
    __shared__ __align__(16) char smem[145664];
    char* ldsA = smem;
    char* ldsB = smem + 32768;                 // 3 buffers x 32 KB
    float* rowmin = (float*)(smem + 131072);   // [8][64]
    float* thrbuf = (float*)(smem + 133120);   // [64]
    unsigned* wl_all = (unsigned*)(smem + 133376);

    const int tid = threadIdx.x;
    const int lane = tid & 63;
    const int wave = tid >> 6;     // 0..15
    const int wm = wave & 1;       // 32-row half
    const int wn = wave >> 1;      // 0..7 col-64 group
    const int lhi = lane >> 4;
    const int llo = lane & 15;

    const int rt = blockIdx.x;     // 256 blocks, 64-row bands
    const int row0 = rt * 64;

    // ---- prologue: stage A band (32 KB) + first two B slices, full drain ----
    #pragma unroll
    for (int i = 0; i < 2; ++i) {
        const int c = wave * 2 + i;            // 0..31: gl = c>>3, kb2 = c&7
        gload16((const char*)z_t + (((size_t)((rt * 4 + (c >> 3)) * 8 + (c & 7))) << 10) + lane * 16,
                ldsA + c * 1024);
    }
    auto STAGE_B = [&](int b, int ct_, int kb2_) {
        #pragma unroll
        for (int i = 0; i < 2; ++i) {
            const int c = wave * 2 + i;        // col-16-group 0..31
            gload16((const char*)cb_t + (((size_t)((ct_ * 32 + c) * 8 + kb2_)) << 10) + lane * 16,
                    ldsB + b * 32768 + c * 1024);
        }
    };
    STAGE_B(0, 0, 0);
    STAGE_B(1, 0, 1);
    if (tid < 64) thrbuf[tid] = 3.0e38f;
    __syncthreads();   // A + B0 + B1 landed

    unsigned* wl = wl_all + wave * SEG;
    float rm[2][4];
    #pragma unroll
    for (int fm = 0; fm < 2; ++fm)
        #pragma unroll
        for (int rg = 0; rg < 4; ++rg) rm[fm][rg] = 3.0e38f;

    int S3 = 0;   // (ci*8 + kb2) % 3, maintained incrementally

    #pragma unroll 1
    for (int ci = 0; ci < NCT; ++ci) {
        f32x4 acc[2][4];
        #pragma unroll
        for (int i = 0; i < 2; ++i)
            #pragma unroll
            for (int j = 0; j < 4; ++j) { acc[i][j][0]=0.f; acc[i][j][1]=0.f; acc[i][j][2]=0.f; acc[i][j][3]=0.f; }

        // ---- K loop: 8 steps of K=32, 3-buffer lookahead-2, counted vmcnt ----
        #pragma unroll
        for (int kb2 = 0; kb2 < 8; ++kb2) {
            const int Sg = ci * 8 + kb2;
            int tb = S3 + 2; if (tb >= 3) tb -= 3;
            const int nS = Sg + 2;
            if (nS < NCT * 8) STAGE_B(tb, nS >> 3, nS & 7);

            // block-min merge over tiles 0..ci-1 (ordered by step barriers + lgkm drain)
            if (kb2 == 1 && ci > 0 && tid < 64) {
                float a = rowmin[tid];
                #pragma unroll
                for (int q = 1; q < 8; ++q) a = fminf(a, rowmin[q * 64 + tid]);
                thrbuf[tid] = fminf(thrbuf[tid], a);
            }

            char* bufB = ldsB + S3 * 32768;
            short8 bfr[4];
            #pragma unroll
            for (int fn = 0; fn < 4; ++fn)
                bfr[fn] = *reinterpret_cast<const short8*>(bufB + (wn * 4 + fn) * 1024 + lane * 16);
            #pragma unroll
            for (int fm = 0; fm < 2; ++fm) {
                const short8 af = *reinterpret_cast<const short8*>(
                    ldsA + (((wm * 2 + fm) * 8) + kb2) * 1024 + lane * 16);
                #pragma unroll
                for (int fn = 0; fn < 4; ++fn)
                    acc[fm][fn] = __builtin_amdgcn_mfma_f32_16x16x32_bf16(af, bfr[fn], acc[fm][fn], 0, 0, 0);
            }

            // counted-vmcnt barrier: this step's 2 stage-loads stay in flight
            if (Sg >= NCT * 8 - 2) asm volatile("s_waitcnt vmcnt(0) lgkmcnt(0)" ::: "memory");
            else                   asm volatile("s_waitcnt vmcnt(2) lgkmcnt(0)" ::: "memory");
            __builtin_amdgcn_s_barrier();
            __builtin_amdgcn_sched_barrier(0);

            S3 = (S3 == 2) ? 0 : S3 + 1;
        }

        // ---- barrier-free epilogue: min update + emission (unchanged from r13) ----
        const int c0 = ci * 512 + wn * 64 + llo;
        float e2c[4];
        #pragma unroll
        for (int fn = 0; fn < 4; ++fn) e2c[fn] = e2g[c0 + fn * 16];

        unsigned wcount = 0;
        #pragma unroll
        for (int fm = 0; fm < 2; ++fm) {
            #pragma unroll
            for (int rg = 0; rg < 4; ++rg) {
                const int rl = wm * 32 + fm * 16 + lhi * 4 + rg;
                float d[4];
                #pragma unroll
                for (int fn = 0; fn < 4; ++fn) d[fn] = fmaf(-2.0f, acc[fm][fn][rg], e2c[fn]);
                float m = fminf(fminf(d[0], d[1]), fminf(d[2], d[3]));
                #pragma unroll
                for (int off = 1; off < 16; off <<= 1) m = fminf(m, __shfl_xor(m, off));
                const float rmv = fminf(rm[fm][rg], m);
                rm[fm][rg] = rmv;
                if (llo == 0) rowmin[wn * 64 + rl] = rmv;
                const float thr = fminf(rmv, thrbuf[rl]) + MARGIN;
                const bool hit = (d[0] <= thr) | (d[1] <= thr) | (d[2] <= thr) | (d[3] <= thr);
                if (__any(hit)) {
                    const int grow = row0 + rl;
                    #pragma unroll
                    for (int fn = 0; fn < 4; ++fn) {
                        const bool p = d[fn] <= thr;
                        const unsigned long long mask = __ballot(p);
                        if (mask) {
                            if (p) {
                                const unsigned pos = wcount + mbcnt64(mask);
                                const unsigned v = ((unsigned)grow << 13) | (unsigned)(c0 + fn * 16);
                                if (pos < SEG) wl[pos] = v;
                                else exact_rescore(z, cbp, z2g, e2g, grow, c0 + fn * 16, best);
                            }
                            wcount += (unsigned)__popcll(mask);
                        }
                    }
                }
            }
        }

        // per-tile flush: one atomic per wave to its shard
        const unsigned n = wcount < SEG ? wcount : SEG;
        unsigned base = 0;
        if (lane == 0 && n) base = atomicAdd(&counters[wave * 16], n);
        base = (unsigned)__shfl((int)base, 0);
        for (unsigned i = lane; i < n; i += 64) {
            const unsigned v = wl[i];
            const unsigned slot = base + i;
            if (slot < C16) list[(size_t)wave * C16 + slot] = v;
            else exact_rescore(z, cbp, z2g, e2g, (int)(v >> 13), (int)(v & 8191u), best);
        }
    }
}

// ---------------- exact rescore of sharded candidate lists (wave per candidate) ----------------
__global__ __launch_bounds__(256) void k_rescore(
    const float* __restrict__ z, const float* __restrict__ cbp,
    const float* __restrict__ z2g, const float* __restrict__ e2g,
    const unsigned* __restrict__ list, const unsigned* __restrict__ counters, unsigned C16,
    unsigned long long* best)
{
    const unsigned wid = (blockIdx.x * blockDim.x + threadIdx.x) >> 6;
    const unsigned nw = (gridDim.x * blockDim.x) >> 6;
    const int lane = threadIdx.x & 63;
    #pragma unroll 1
    for (int s = 0; s < 16; ++s) {
        const unsigned n = min(counters[s * 16], C16);
        const unsigned* shard = list + (size_t)s * C16;
        for (unsigned i = wid; i < n; i += nw) {
            const unsigned v = shard[i];
            const unsigned row = v >> 13, col = v & 8191u;
            const float4 a = *reinterpret_cast<const float4*>(z + (size_t)row * DDIM + lane * 4);
            const float4 b = *reinterpret_cast<const float4*>(cbp + (size_t)col * DDIM + lane * 4);
            float sdot = fmaf(a.x, b.x, fmaf(a.y, b.y, fmaf(a.z, b.z, a.w * b.w)));
            #pragma unroll
            for (int off = 1; off < 64; off <<= 1) sdot += __shfl_xor(sdot, off);
            if (lane == 0) {
                const float de = z2g[row] + e2g[col] - 2.0f * sdot;
                const unsigned long long key =
                    ((unsigned long long)__float_as_uint(de) << 32) | col;
                atomicMin(&best[row], key);
            }
        }
    }
}

// ---------------- gather + z_st + loss + final scalars (ticket) ----------------
__global__ __launch_bounds__(1024) void k_gather(
    const float* __restrict__ z, const float* __restrict__ cbp,
    const unsigned long long* __restrict__ best,
    float* __restrict__ out, float* __restrict__ accum, unsigned* __restrict__ gctr)
{
    __shared__ float wsum[16];
    const int tid = threadIdx.x;
    const int row = blockIdx.x * 16 + (tid >> 6);
    const int lane = tid & 63;
    const unsigned k = (unsigned)(best[row] & 0xFFFFFFFFull);
    const float4 ze = *reinterpret_cast<const float4*>(z + (size_t)row * DDIM + lane * 4);
    const float4 cq = *reinterpret_cast<const float4*>(cbp + (size_t)k * DDIM + lane * 4);
    float4 zst;
    zst.x = ze.x + (cq.x - ze.x); zst.y = ze.y + (cq.y - ze.y);
    zst.z = ze.z + (cq.z - ze.z); zst.w = ze.w + (cq.w - ze.w);
    *reinterpret_cast<float4*>(out + (size_t)row * DDIM + lane * 4) = zst;
    const float dx = cq.x - ze.x, dy = cq.y - ze.y, dz = cq.z - ze.z, dw = cq.w - ze.w;
    float s = dx * dx + dy * dy + dz * dz + dw * dw;
    #pragma unroll
    for (int off = 32; off > 0; off >>= 1) s += __shfl_down(s, off);
    if (lane == 0) {
        wsum[tid >> 6] = s;
        out[(size_t)NROWS * DDIM + row] = (float)k;
    }
    __syncthreads();
    if (tid == 0) {
        float tot = 0.f;
        #pragma unroll
        for (int i = 0; i < 16; ++i) tot += wsum[i];
        atomicAdd(accum, tot);
        __threadfence();
        const unsigned t = atomicAdd(gctr, 1u);
        if (t == GATHER_BLOCKS - 1) {
            const float total = atomicAdd(accum, 0.0f);
            const float m = total / (float)(NROWS * DDIM);
            out[(size_t)NROWS * DDIM + NROWS + 0] = m;
            out[(size_t)NROWS * DDIM + NROWS + 1] = m;
        }
    }
}

extern "C" void kernel_launch(void* const* d_in, const int* in_sizes, int n_in,
                              void* d_out, int out_size, void* d_ws, size_t ws_size,
                              hipStream_t stream)
{
    const float* z  = (const float*)d_in[0];
    const float* cb = (const float*)d_in[1];
    float* out = (float*)d_out;

    // bf16 pre-tiled scratch lives in d_out's z_st region (12 MB of 16.8 MB),
    // consumed by k_screen/k_rescore and fully overwritten afterwards by k_gather.
    unsigned short* z_t  = (unsigned short*)d_out;                      // 8 MB
    unsigned short* cb_t = (unsigned short*)((char*)d_out + 8388608);   // 4 MB

    char* ws = (char*)d_ws;
    unsigned long long* best = (unsigned long long*)ws;   // 131072 B
    float* e2      = (float*)(ws + 131072);               // 32768 B
    float* z2      = (float*)(ws + 163840);               // 65536 B
    float* accum   = (float*)(ws + 229376);
    unsigned* gctr = (unsigned*)(ws + 229380);
    unsigned* counters = (unsigned*)(ws + 229440);        // 16 shard counters, 64B apart
    unsigned* list = (unsigned*)(ws + 230464);
    unsigned C16 = 0;
    if (ws_size > 230464 + 64) {
        size_t c = (ws_size - 230464) / 4 / 16;
        if (c > (1u << 19)) c = (1u << 19);
        C16 = (unsigned)c;
    }

    k_convert<<<384, 256, 0, stream>>>(z, z_t, cb, cb_t, z2, e2, best, accum, counters, gctr);
    k_screen<<<256, 1024, 0, stream>>>(z, cb, z_t, cb_t, z2, e2, best, counters, list, C16);
    k_rescore<<<2048, 256, 0, stream>>>(z, cb, z2, e2, list, counters, C16, best);
    k_gather<<<GATHER_BLOCKS, 1024, 0, stream>>>(z, cb, best, out, accum, gctr);
}

// Round 16
// 214.722 us; speedup vs baseline: 1.3226x; 1.1629x over previous
//
#include <hip/hip_runtime.h>

#define NROWS 16384
#define KCODES 8192
#define DDIM 256
#define MARGIN 2.0f
#define SEG 192
#define NCT 16     // 512-col tiles (block sweeps all 8192 cols)
#define GATHER_BLOCKS (NROWS / 16)

typedef __attribute__((ext_vector_type(8))) short short8;
typedef __attribute__((ext_vector_type(4))) float f32x4;

// ---------------- helpers ----------------
__device__ inline unsigned short f2bf(float x) {
    unsigned u = __float_as_uint(x);
    return (unsigned short)((u + 0x7FFFu + ((u >> 16) & 1u)) >> 16);  // RNE
}

__device__ inline void gload16(const void* g, void* l) {
    __builtin_amdgcn_global_load_lds(
        (const __attribute__((address_space(1))) unsigned char*)g,
        (__attribute__((address_space(3))) unsigned char*)l, 16, 0, 0);
}

__device__ inline unsigned mbcnt64(unsigned long long m) {
    unsigned lo = __builtin_amdgcn_mbcnt_lo((unsigned)m, 0u);
    return __builtin_amdgcn_mbcnt_hi((unsigned)(m >> 32), lo);
}

__device__ inline void exact_rescore(const float* __restrict__ z, const float* __restrict__ cb,
                                     const float* __restrict__ z2g, const float* __restrict__ e2g,
                                     int grow, int gcol, unsigned long long* best) {
    const float4* av = reinterpret_cast<const float4*>(z + (size_t)grow * DDIM);
    const float4* bv = reinterpret_cast<const float4*>(cb + (size_t)gcol * DDIM);
    float dot = 0.f;
    #pragma unroll 8
    for (int j = 0; j < 64; ++j) {
        const float4 xa = av[j], xb = bv[j];
        dot = fmaf(xa.x, xb.x, fmaf(xa.y, xb.y, fmaf(xa.z, xb.z, fmaf(xa.w, xb.w, dot))));
    }
    const float de = z2g[grow] + e2g[gcol] - 2.0f * dot;
    const unsigned long long key =
        ((unsigned long long)__float_as_uint(de) << 32) | (unsigned)gcol;
    atomicMin(best + grow, key);
}

// ---------------- convert fp32 -> bf16 pre-tiled fragment layout + fused sumsq ----------------
__global__ __launch_bounds__(256) void k_convert(
    const float* __restrict__ z, unsigned short* __restrict__ z_t,
    const float* __restrict__ cb, unsigned short* __restrict__ cb_t,
    float* __restrict__ z2, float* __restrict__ e2,
    unsigned long long* best, float* accum, unsigned* counters, unsigned* gctr)
{
    const int tid = threadIdx.x;
    const int bx = blockIdx.x;
    if (bx < 64) {
        const int gid = bx * 256 + tid;
        best[gid] = 0xFFFFFFFFFFFFFFFFull;
    }
    if (bx == 0) {
        if (tid < 16) counters[tid * 16] = 0u;
        if (tid == 0) { accum[0] = 0.0f; gctr[0] = 0u; }
    }
    const float* in;
    unsigned short* outt;
    float* sumsq;
    int g;
    if (bx < 256) { in = z;  outt = z_t;  sumsq = z2; g = bx * 4 + (tid >> 6); }
    else          { in = cb; outt = cb_t; sumsq = e2; g = (bx - 256) * 4 + (tid >> 6); }
    const int lane = tid & 63;
    const int row = g * 16 + (lane & 15);
    const int ko = (lane >> 4) * 8;
    float ss = 0.f;
    #pragma unroll
    for (int kb2 = 0; kb2 < 8; ++kb2) {
        const float4* src = reinterpret_cast<const float4*>(in + (size_t)row * DDIM + kb2 * 32 + ko);
        const float4 a = src[0], b = src[1];
        ss += a.x * a.x + a.y * a.y + a.z * a.z + a.w * a.w
            + b.x * b.x + b.y * b.y + b.z * b.z + b.w * b.w;
        short8 p;
        p[0] = (short)f2bf(a.x); p[1] = (short)f2bf(a.y); p[2] = (short)f2bf(a.z); p[3] = (short)f2bf(a.w);
        p[4] = (short)f2bf(b.x); p[5] = (short)f2bf(b.y); p[6] = (short)f2bf(b.z); p[7] = (short)f2bf(b.w);
        *reinterpret_cast<short8*>(outt + (((size_t)(g * 8 + kb2)) << 9) + lane * 8) = p;
    }
    ss += __shfl_xor(ss, 16);
    ss += __shfl_xor(ss, 32);
    if (lane < 16) sumsq[g * 16 + lane] = ss;
}

// ---------------- MFMA screen: r15 K-loop + block-tight 2-barrier epilogue ----------------
// 64 rows x ALL 8192 cols per block; wave tile 32x64 (acc[2][4], no-spill).
// K-loop: 3-buffer lookahead-2, s_barrier + vmcnt(2) (counted; loads span barriers).
// Epilogue: phase A rowmin write -> lgkm barrier -> wave0 merge (incl. current tile)
//           -> lgkm barrier -> phase B emit vs thrbuf+MARGIN. No vmcnt drain in epilogue.
// LDS: A 32K @0 | B 3x32K @32768 | rowmin[8][64] @131072 | thrbuf[64] @133120 | wl 16xSEG @133376
__global__ __launch_bounds__(1024, 4) void k_screen(
    const float* __restrict__ z, const float* __restrict__ cbp,
    const unsigned short* __restrict__ z_t, const unsigned short* __restrict__ cb_t,
    const float* __restrict__ z2g, const float* __restrict__ e2g,
    unsigned long long* __restrict__ best,
    unsigned* __restrict__ counters, unsigned* __restrict__ list, unsigned C16)
{
    __shared__ __align__(16) char smem[145664];
    char* ldsA = smem;
    char* ldsB = smem + 32768;                 // 3 buffers x 32 KB
    float* rowmin = (float*)(smem + 131072);   // [8][64] current-tile per-wave row mins
    float* thrbuf = (float*)(smem + 133120);   // [64] running block min (incl. current tile)
    unsigned* wl_all = (unsigned*)(smem + 133376);

    const int tid = threadIdx.x;
    const int lane = tid & 63;
    const int wave = tid >> 6;     // 0..15
    const int wm = wave & 1;       // 32-row half
    const int wn = wave >> 1;      // 0..7 col-64 group
    const int lhi = lane >> 4;
    const int llo = lane & 15;

    const int rt = blockIdx.x;     // 256 blocks, 64-row bands
    const int row0 = rt * 64;

    // ---- prologue: stage A band (32 KB) + first two B slices, full drain ----
    #pragma unroll
    for (int i = 0; i < 2; ++i) {
        const int c = wave * 2 + i;            // 0..31: gl = c>>3, kb2 = c&7
        gload16((const char*)z_t + (((size_t)((rt * 4 + (c >> 3)) * 8 + (c & 7))) << 10) + lane * 16,
                ldsA + c * 1024);
    }
    auto STAGE_B = [&](int b, int ct_, int kb2_) {
        #pragma unroll
        for (int i = 0; i < 2; ++i) {
            const int c = wave * 2 + i;        // col-16-group 0..31
            gload16((const char*)cb_t + (((size_t)((ct_ * 32 + c) * 8 + kb2_)) << 10) + lane * 16,
                    ldsB + b * 32768 + c * 1024);
        }
    };
    STAGE_B(0, 0, 0);
    STAGE_B(1, 0, 1);
    if (tid < 64) thrbuf[tid] = 3.0e38f;
    __syncthreads();   // A + B0 + B1 landed

    unsigned* wl = wl_all + wave * SEG;
    int S3 = 0;   // (ci*8 + kb2) % 3, maintained incrementally

    #pragma unroll 1
    for (int ci = 0; ci < NCT; ++ci) {
        f32x4 acc[2][4];
        #pragma unroll
        for (int i = 0; i < 2; ++i)
            #pragma unroll
            for (int j = 0; j < 4; ++j) { acc[i][j][0]=0.f; acc[i][j][1]=0.f; acc[i][j][2]=0.f; acc[i][j][3]=0.f; }

        // ---- K loop: 8 steps of K=32, 3-buffer lookahead-2, counted vmcnt ----
        #pragma unroll
        for (int kb2 = 0; kb2 < 8; ++kb2) {
            const int Sg = ci * 8 + kb2;
            int tb = S3 + 2; if (tb >= 3) tb -= 3;
            const int nS = Sg + 2;
            if (nS < NCT * 8) STAGE_B(tb, nS >> 3, nS & 7);

            char* bufB = ldsB + S3 * 32768;
            short8 bfr[4];
            #pragma unroll
            for (int fn = 0; fn < 4; ++fn)
                bfr[fn] = *reinterpret_cast<const short8*>(bufB + (wn * 4 + fn) * 1024 + lane * 16);
            #pragma unroll
            for (int fm = 0; fm < 2; ++fm) {
                const short8 af = *reinterpret_cast<const short8*>(
                    ldsA + (((wm * 2 + fm) * 8) + kb2) * 1024 + lane * 16);
                #pragma unroll
                for (int fn = 0; fn < 4; ++fn)
                    acc[fm][fn] = __builtin_amdgcn_mfma_f32_16x16x32_bf16(af, bfr[fn], acc[fm][fn], 0, 0, 0);
            }

            // counted-vmcnt barrier: this step's 2 stage-loads stay in flight
            if (Sg >= NCT * 8 - 2) asm volatile("s_waitcnt vmcnt(0) lgkmcnt(0)" ::: "memory");
            else                   asm volatile("s_waitcnt vmcnt(2) lgkmcnt(0)" ::: "memory");
            __builtin_amdgcn_s_barrier();
            __builtin_amdgcn_sched_barrier(0);

            S3 = (S3 == 2) ? 0 : S3 + 1;
        }

        // ---- epilogue: block-tight threshold (2 lgkm-only barriers, no vmcnt drain) ----
        const int c0 = ci * 512 + wn * 64 + llo;
        float e2c[4];
        #pragma unroll
        for (int fn = 0; fn < 4; ++fn) e2c[fn] = e2g[c0 + fn * 16];

        // phase A: per-wave per-row min over this tile's 64-col slice
        #pragma unroll
        for (int fm = 0; fm < 2; ++fm) {
            #pragma unroll
            for (int rg = 0; rg < 4; ++rg) {
                const int rl = wm * 32 + fm * 16 + lhi * 4 + rg;
                float d[4];
                #pragma unroll
                for (int fn = 0; fn < 4; ++fn) d[fn] = fmaf(-2.0f, acc[fm][fn][rg], e2c[fn]);
                float m = fminf(fminf(d[0], d[1]), fminf(d[2], d[3]));
                #pragma unroll
                for (int off = 1; off < 16; off <<= 1) m = fminf(m, __shfl_xor(m, off));
                if (llo == 0) rowmin[wn * 64 + rl] = m;
            }
        }
        asm volatile("s_waitcnt lgkmcnt(0)" ::: "memory");
        __builtin_amdgcn_s_barrier();
        __builtin_amdgcn_sched_barrier(0);

        // merge: running block min now INCLUDES the current tile
        if (tid < 64) {
            float a = rowmin[tid];
            #pragma unroll
            for (int q = 1; q < 8; ++q) a = fminf(a, rowmin[q * 64 + tid]);
            thrbuf[tid] = fminf(thrbuf[tid], a);
        }
        asm volatile("s_waitcnt lgkmcnt(0)" ::: "memory");
        __builtin_amdgcn_s_barrier();
        __builtin_amdgcn_sched_barrier(0);

        // phase B: emit vs tight threshold (recompute d from acc, 4 fmaf each)
        unsigned wcount = 0;
        #pragma unroll
        for (int fm = 0; fm < 2; ++fm) {
            #pragma unroll
            for (int rg = 0; rg < 4; ++rg) {
                const int rl = wm * 32 + fm * 16 + lhi * 4 + rg;
                const float thr = thrbuf[rl] + MARGIN;
                float d[4];
                #pragma unroll
                for (int fn = 0; fn < 4; ++fn) d[fn] = fmaf(-2.0f, acc[fm][fn][rg], e2c[fn]);
                const bool hit = (d[0] <= thr) | (d[1] <= thr) | (d[2] <= thr) | (d[3] <= thr);
                if (__any(hit)) {
                    const int grow = row0 + rl;
                    #pragma unroll
                    for (int fn = 0; fn < 4; ++fn) {
                        const bool p = d[fn] <= thr;
                        const unsigned long long mask = __ballot(p);
                        if (mask) {
                            if (p) {
                                const unsigned pos = wcount + mbcnt64(mask);
                                const unsigned v = ((unsigned)grow << 13) | (unsigned)(c0 + fn * 16);
                                if (pos < SEG) wl[pos] = v;
                                else exact_rescore(z, cbp, z2g, e2g, grow, c0 + fn * 16, best);
                            }
                            wcount += (unsigned)__popcll(mask);
                        }
                    }
                }
            }
        }

        // per-tile flush: one atomic per wave to its shard
        const unsigned n = wcount < SEG ? wcount : SEG;
        unsigned base = 0;
        if (lane == 0 && n) base = atomicAdd(&counters[wave * 16], n);
        base = (unsigned)__shfl((int)base, 0);
        for (unsigned i = lane; i < n; i += 64) {
            const unsigned v = wl[i];
            const unsigned slot = base + i;
            if (slot < C16) list[(size_t)wave * C16 + slot] = v;
            else exact_rescore(z, cbp, z2g, e2g, (int)(v >> 13), (int)(v & 8191u), best);
        }
    }
}

// ---------------- exact rescore of sharded candidate lists (wave per candidate) ----------------
__global__ __launch_bounds__(256) void k_rescore(
    const float* __restrict__ z, const float* __restrict__ cbp,
    const float* __restrict__ z2g, const float* __restrict__ e2g,
    const unsigned* __restrict__ list, const unsigned* __restrict__ counters, unsigned C16,
    unsigned long long* best)
{
    const unsigned wid = (blockIdx.x * blockDim.x + threadIdx.x) >> 6;
    const unsigned nw = (gridDim.x * blockDim.x) >> 6;
    const int lane = threadIdx.x & 63;
    #pragma unroll 1
    for (int s = 0; s < 16; ++s) {
        const unsigned n = min(counters[s * 16], C16);
        const unsigned* shard = list + (size_t)s * C16;
        for (unsigned i = wid; i < n; i += nw) {
            const unsigned v = shard[i];
            const unsigned row = v >> 13, col = v & 8191u;
            const float4 a = *reinterpret_cast<const float4*>(z + (size_t)row * DDIM + lane * 4);
            const float4 b = *reinterpret_cast<const float4*>(cbp + (size_t)col * DDIM + lane * 4);
            float sdot = fmaf(a.x, b.x, fmaf(a.y, b.y, fmaf(a.z, b.z, a.w * b.w)));
            #pragma unroll
            for (int off = 1; off < 64; off <<= 1) sdot += __shfl_xor(sdot, off);
            if (lane == 0) {
                const float de = z2g[row] + e2g[col] - 2.0f * sdot;
                const unsigned long long key =
                    ((unsigned long long)__float_as_uint(de) << 32) | col;
                atomicMin(&best[row], key);
            }
        }
    }
}

// ---------------- gather + z_st + loss + final scalars (ticket) ----------------
__global__ __launch_bounds__(1024) void k_gather(
    const float* __restrict__ z, const float* __restrict__ cbp,
    const unsigned long long* __restrict__ best,
    float* __restrict__ out, float* __restrict__ accum, unsigned* __restrict__ gctr)
{
    __shared__ float wsum[16];
    const int tid = threadIdx.x;
    const int row = blockIdx.x * 16 + (tid >> 6);
    const int lane = tid & 63;
    const unsigned k = (unsigned)(best[row] & 0xFFFFFFFFull);
    const float4 ze = *reinterpret_cast<const float4*>(z + (size_t)row * DDIM + lane * 4);
    const float4 cq = *reinterpret_cast<const float4*>(cbp + (size_t)k * DDIM + lane * 4);
    float4 zst;
    zst.x = ze.x + (cq.x - ze.x); zst.y = ze.y + (cq.y - ze.y);
    zst.z = ze.z + (cq.z - ze.z); zst.w = ze.w + (cq.w - ze.w);
    *reinterpret_cast<float4*>(out + (size_t)row * DDIM + lane * 4) = zst;
    const float dx = cq.x - ze.x, dy = cq.y - ze.y, dz = cq.z - ze.z, dw = cq.w - ze.w;
    float s = dx * dx + dy * dy + dz * dz + dw * dw;
    #pragma unroll
    for (int off = 32; off > 0; off >>= 1) s += __shfl_down(s, off);
    if (lane == 0) {
        wsum[tid >> 6] = s;
        out[(size_t)NROWS * DDIM + row] = (float)k;
    }
    __syncthreads();
    if (tid == 0) {
        float tot = 0.f;
        #pragma unroll
        for (int i = 0; i < 16; ++i) tot += wsum[i];
        atomicAdd(accum, tot);
        __threadfence();
        const unsigned t = atomicAdd(gctr, 1u);
        if (t == GATHER_BLOCKS - 1) {
            const float total = atomicAdd(accum, 0.0f);
            const float m = total / (float)(NROWS * DDIM);
            out[(size_t)NROWS * DDIM + NROWS + 0] = m;
            out[(size_t)NROWS * DDIM + NROWS + 1] = m;
        }
    }
}

extern "C" void kernel_launch(void* const* d_in, const int* in_sizes, int n_in,
                              void* d_out, int out_size, void* d_ws, size_t ws_size,
                              hipStream_t stream)
{
    const float* z  = (const float*)d_in[0];
    const float* cb = (const float*)d_in[1];
    float* out = (float*)d_out;

    // bf16 pre-tiled scratch lives in d_out's z_st region (12 MB of 16.8 MB),
    // consumed by k_screen/k_rescore and fully overwritten afterwards by k_gather.
    unsigned short* z_t  = (unsigned short*)d_out;                      // 8 MB
    unsigned short* cb_t = (unsigned short*)((char*)d_out + 8388608);   // 4 MB

    char* ws = (char*)d_ws;
    unsigned long long* best = (unsigned long long*)ws;   // 131072 B
    float* e2      = (float*)(ws + 131072);               // 32768 B
    float* z2      = (float*)(ws + 163840);               // 65536 B
    float* accum   = (float*)(ws + 229376);
    unsigned* gctr = (unsigned*)(ws + 229380);
    unsigned* counters = (unsigned*)(ws + 229440);        // 16 shard counters, 64B apart
    unsigned* list = (unsigned*)(ws + 230464);
    unsigned C16 = 0;
    if (ws_size > 230464 + 64) {
        size_t c = (ws_size - 230464) / 4 / 16;
        if (c > (1u << 19)) c = (1u << 19);
        C16 = (unsigned)c;
    }

    k_convert<<<384, 256, 0, stream>>>(z, z_t, cb, cb_t, z2, e2, best, accum, counters, gctr);
    k_screen<<<256, 1024, 0, stream>>>(z, cb, z_t, cb_t, z2, e2, best, counters, list, C16);
    k_rescore<<<1024, 256, 0, stream>>>(z, cb, z2, e2, list, counters, C16, best);
    k_gather<<<GATHER_BLOCKS, 1024, 0, stream>>>(z, cb, best, out, accum, gctr);
}

// Round 17
// 212.274 us; speedup vs baseline: 1.3378x; 1.0115x over previous
//
#include <hip/hip_runtime.h>

#define NROWS 16384
#define KCODES 8192
#define DDIM 256
#define MARGIN 1.0f
#define SEG 192
#define NCT 16     // 512-col tiles (block sweeps all 8192 cols)
#define GATHER_BLOCKS (NROWS / 16)

typedef __attribute__((ext_vector_type(8))) short short8;
typedef __attribute__((ext_vector_type(4))) float f32x4;

// ---------------- helpers ----------------
__device__ inline unsigned short f2bf(float x) {
    unsigned u = __float_as_uint(x);
    return (unsigned short)((u + 0x7FFFu + ((u >> 16) & 1u)) >> 16);  // RNE
}

__device__ inline void gload16(const void* g, void* l) {
    __builtin_amdgcn_global_load_lds(
        (const __attribute__((address_space(1))) unsigned char*)g,
        (__attribute__((address_space(3))) unsigned char*)l, 16, 0, 0);
}

__device__ inline unsigned mbcnt64(unsigned long long m) {
    unsigned lo = __builtin_amdgcn_mbcnt_lo((unsigned)m, 0u);
    return __builtin_amdgcn_mbcnt_hi((unsigned)(m >> 32), lo);
}

__device__ inline void exact_rescore(const float* __restrict__ z, const float* __restrict__ cb,
                                     const float* __restrict__ z2g, const float* __restrict__ e2g,
                                     int grow, int gcol, unsigned long long* best) {
    const float4* av = reinterpret_cast<const float4*>(z + (size_t)grow * DDIM);
    const float4* bv = reinterpret_cast<const float4*>(cb + (size_t)gcol * DDIM);
    float dot = 0.f;
    #pragma unroll 8
    for (int j = 0; j < 64; ++j) {
        const float4 xa = av[j], xb = bv[j];
        dot = fmaf(xa.x, xb.x, fmaf(xa.y, xb.y, fmaf(xa.z, xb.z, fmaf(xa.w, xb.w, dot))));
    }
    const float de = z2g[grow] + e2g[gcol] - 2.0f * dot;
    const unsigned long long key =
        ((unsigned long long)__float_as_uint(de) << 32) | (unsigned)gcol;
    atomicMin(best + grow, key);
}

// ---------------- convert cb fp32 -> bf16 pre-tiled fragment layout + e2 + init ----------------
// chunk (g, kb2): 1 KB, slot s: row g*16 + (s&15), k = kb2*32 + (s>>4)*8 .. +8
__global__ __launch_bounds__(256) void k_convert(
    const float* __restrict__ cb, unsigned short* __restrict__ cb_t,
    float* __restrict__ e2,
    unsigned long long* best, float* accum, unsigned* counters, unsigned* gctr)
{
    const int tid = threadIdx.x;
    const int bx = blockIdx.x;
    if (bx < 64) {
        const int gid = bx * 256 + tid;
        best[gid] = 0xFFFFFFFFFFFFFFFFull;
    }
    if (bx == 0) {
        if (tid < 16) counters[tid * 16] = 0u;
        if (tid == 0) { accum[0] = 0.0f; gctr[0] = 0u; }
    }
    const int g = bx * 4 + (tid >> 6);       // 512 groups over 128 blocks
    const int lane = tid & 63;
    const int row = g * 16 + (lane & 15);
    const int ko = (lane >> 4) * 8;
    float ss = 0.f;
    #pragma unroll
    for (int kb2 = 0; kb2 < 8; ++kb2) {
        const float4* src = reinterpret_cast<const float4*>(cb + (size_t)row * DDIM + kb2 * 32 + ko);
        const float4 a = src[0], b = src[1];
        ss += a.x * a.x + a.y * a.y + a.z * a.z + a.w * a.w
            + b.x * b.x + b.y * b.y + b.z * b.z + b.w * b.w;
        short8 p;
        p[0] = (short)f2bf(a.x); p[1] = (short)f2bf(a.y); p[2] = (short)f2bf(a.z); p[3] = (short)f2bf(a.w);
        p[4] = (short)f2bf(b.x); p[5] = (short)f2bf(b.y); p[6] = (short)f2bf(b.z); p[7] = (short)f2bf(b.w);
        *reinterpret_cast<short8*>(cb_t + (((size_t)(g * 8 + kb2)) << 9) + lane * 8) = p;
    }
    ss += __shfl_xor(ss, 16);
    ss += __shfl_xor(ss, 32);
    if (lane < 16) e2[g * 16 + lane] = ss;
}

// ---------------- MFMA screen: fused z-convert prologue + r16 K-loop/epilogue ----------------
// 64 rows x ALL 8192 cols per block; wave tile 32x64 (acc[2][4], no-spill).
// Prologue: read own 64-row fp32 z band, convert to bf16 fragments DIRECTLY into ldsA
//           (no z_t global round-trip); compute z2 for own band.
// K-loop: 3-buffer lookahead-2, s_barrier + counted vmcnt(2).
// Epilogue: 2 lgkm-only barriers -> block-tight running threshold -> ballot emit.
// LDS: A 32K @0 | B 3x32K @32768 | rowmin[8][64] @131072 | thrbuf[64] @133120 | wl 16xSEG @133376
__global__ __launch_bounds__(1024, 4) void k_screen(
    const float* __restrict__ z, const float* __restrict__ cbp,
    const unsigned short* __restrict__ cb_t,
    float* z2g, const float* __restrict__ e2g,
    unsigned long long* __restrict__ best,
    unsigned* __restrict__ counters, unsigned* __restrict__ list, unsigned C16)
{
    __shared__ __align__(16) char smem[145664];
    char* ldsA = smem;
    char* ldsB = smem + 32768;                 // 3 buffers x 32 KB
    float* rowmin = (float*)(smem + 131072);   // [8][64]
    float* thrbuf = (float*)(smem + 133120);   // [64] running block min (incl. current tile)
    unsigned* wl_all = (unsigned*)(smem + 133376);

    const int tid = threadIdx.x;
    const int lane = tid & 63;
    const int wave = tid >> 6;     // 0..15
    const int wm = wave & 1;       // 32-row half
    const int wn = wave >> 1;      // 0..7 col-64 group
    const int lhi = lane >> 4;
    const int llo = lane & 15;

    const int rt = blockIdx.x;     // 256 blocks, 64-row bands
    const int row0 = rt * 64;

    // ---- prologue ----
    // (a) first B slices in flight early
    auto STAGE_B = [&](int b, int ct_, int kb2_) {
        #pragma unroll
        for (int i = 0; i < 2; ++i) {
            const int c = wave * 2 + i;        // col-16-group 0..31
            gload16((const char*)cb_t + (((size_t)((ct_ * 32 + c) * 8 + kb2_)) << 10) + lane * 16,
                    ldsB + b * 32768 + c * 1024);
        }
    };
    STAGE_B(0, 0, 0);
    STAGE_B(1, 0, 1);

    // (b) fused z-convert: fp32 band -> bf16 fragments straight into ldsA (2 slots/thread)
    {
        const int c = tid >> 5;                // chunk 0..31: gl = c>>3, kb2 = c&7
        const int gl = c >> 3, kb2 = c & 7;
        const int sp = (tid & 31) * 2;
        #pragma unroll
        for (int i = 0; i < 2; ++i) {
            const int s = sp + i;
            const int row = gl * 16 + (s & 15);
            const int k = kb2 * 32 + (s >> 4) * 8;
            const float4* src = reinterpret_cast<const float4*>(z + (size_t)(row0 + row) * DDIM + k);
            const float4 a = src[0], b = src[1];
            short8 p;
            p[0] = (short)f2bf(a.x); p[1] = (short)f2bf(a.y); p[2] = (short)f2bf(a.z); p[3] = (short)f2bf(a.w);
            p[4] = (short)f2bf(b.x); p[5] = (short)f2bf(b.y); p[6] = (short)f2bf(b.z); p[7] = (short)f2bf(b.w);
            *reinterpret_cast<short8*>(ldsA + c * 1024 + s * 16) = p;
        }
    }

    // (c) z2 for own band (used by rescore keys; additive per-row constant)
    #pragma unroll
    for (int rr = 0; rr < 4; ++rr) {
        const int row = wave * 4 + rr;
        const float4 v = *reinterpret_cast<const float4*>(z + (size_t)(row0 + row) * DDIM + lane * 4);
        float s = v.x * v.x + v.y * v.y + v.z * v.z + v.w * v.w;
        #pragma unroll
        for (int off = 1; off < 64; off <<= 1) s += __shfl_xor(s, off);
        if (lane == 0) z2g[row0 + row] = s;
    }

    if (tid < 64) thrbuf[tid] = 3.0e38f;
    __syncthreads();   // ldsA writes + B0/B1 + z2 writes all complete

    unsigned* wl = wl_all + wave * SEG;
    int S3 = 0;   // (ci*8 + kb2) % 3

    #pragma unroll 1
    for (int ci = 0; ci < NCT; ++ci) {
        f32x4 acc[2][4];
        #pragma unroll
        for (int i = 0; i < 2; ++i)
            #pragma unroll
            for (int j = 0; j < 4; ++j) { acc[i][j][0]=0.f; acc[i][j][1]=0.f; acc[i][j][2]=0.f; acc[i][j][3]=0.f; }

        // ---- K loop: 8 steps of K=32, 3-buffer lookahead-2, counted vmcnt ----
        #pragma unroll
        for (int kb2 = 0; kb2 < 8; ++kb2) {
            const int Sg = ci * 8 + kb2;
            int tb = S3 + 2; if (tb >= 3) tb -= 3;
            const int nS = Sg + 2;
            if (nS < NCT * 8) STAGE_B(tb, nS >> 3, nS & 7);

            char* bufB = ldsB + S3 * 32768;
            short8 bfr[4];
            #pragma unroll
            for (int fn = 0; fn < 4; ++fn)
                bfr[fn] = *reinterpret_cast<const short8*>(bufB + (wn * 4 + fn) * 1024 + lane * 16);
            #pragma unroll
            for (int fm = 0; fm < 2; ++fm) {
                const short8 af = *reinterpret_cast<const short8*>(
                    ldsA + (((wm * 2 + fm) * 8) + kb2) * 1024 + lane * 16);
                #pragma unroll
                for (int fn = 0; fn < 4; ++fn)
                    acc[fm][fn] = __builtin_amdgcn_mfma_f32_16x16x32_bf16(af, bfr[fn], acc[fm][fn], 0, 0, 0);
            }

            // counted-vmcnt barrier: this step's 2 stage-loads stay in flight
            if (Sg >= NCT * 8 - 2) asm volatile("s_waitcnt vmcnt(0) lgkmcnt(0)" ::: "memory");
            else                   asm volatile("s_waitcnt vmcnt(2) lgkmcnt(0)" ::: "memory");
            __builtin_amdgcn_s_barrier();
            __builtin_amdgcn_sched_barrier(0);

            S3 = (S3 == 2) ? 0 : S3 + 1;
        }

        // ---- epilogue: block-tight threshold (2 lgkm-only barriers, no vmcnt drain) ----
        const int c0 = ci * 512 + wn * 64 + llo;
        float e2c[4];
        #pragma unroll
        for (int fn = 0; fn < 4; ++fn) e2c[fn] = e2g[c0 + fn * 16];

        // phase A: per-wave per-row min over this tile's 64-col slice
        #pragma unroll
        for (int fm = 0; fm < 2; ++fm) {
            #pragma unroll
            for (int rg = 0; rg < 4; ++rg) {
                const int rl = wm * 32 + fm * 16 + lhi * 4 + rg;
                float d[4];
                #pragma unroll
                for (int fn = 0; fn < 4; ++fn) d[fn] = fmaf(-2.0f, acc[fm][fn][rg], e2c[fn]);
                float m = fminf(fminf(d[0], d[1]), fminf(d[2], d[3]));
                #pragma unroll
                for (int off = 1; off < 16; off <<= 1) m = fminf(m, __shfl_xor(m, off));
                if (llo == 0) rowmin[wn * 64 + rl] = m;
            }
        }
        asm volatile("s_waitcnt lgkmcnt(0)" ::: "memory");
        __builtin_amdgcn_s_barrier();
        __builtin_amdgcn_sched_barrier(0);

        // merge: running block min now INCLUDES the current tile
        if (tid < 64) {
            float a = rowmin[tid];
            #pragma unroll
            for (int q = 1; q < 8; ++q) a = fminf(a, rowmin[q * 64 + tid]);
            thrbuf[tid] = fminf(thrbuf[tid], a);
        }
        asm volatile("s_waitcnt lgkmcnt(0)" ::: "memory");
        __builtin_amdgcn_s_barrier();
        __builtin_amdgcn_sched_barrier(0);

        // phase B: emit vs tight threshold (recompute d from acc)
        unsigned wcount = 0;
        #pragma unroll
        for (int fm = 0; fm < 2; ++fm) {
            #pragma unroll
            for (int rg = 0; rg < 4; ++rg) {
                const int rl = wm * 32 + fm * 16 + lhi * 4 + rg;
                const float thr = thrbuf[rl] + MARGIN;
                float d[4];
                #pragma unroll
                for (int fn = 0; fn < 4; ++fn) d[fn] = fmaf(-2.0f, acc[fm][fn][rg], e2c[fn]);
                const bool hit = (d[0] <= thr) | (d[1] <= thr) | (d[2] <= thr) | (d[3] <= thr);
                if (__any(hit)) {
                    const int grow = row0 + rl;
                    #pragma unroll
                    for (int fn = 0; fn < 4; ++fn) {
                        const bool p = d[fn] <= thr;
                        const unsigned long long mask = __ballot(p);
                        if (mask) {
                            if (p) {
                                const unsigned pos = wcount + mbcnt64(mask);
                                const unsigned v = ((unsigned)grow << 13) | (unsigned)(c0 + fn * 16);
                                if (pos < SEG) wl[pos] = v;
                                else exact_rescore(z, cbp, z2g, e2g, grow, c0 + fn * 16, best);
                            }
                            wcount += (unsigned)__popcll(mask);
                        }
                    }
                }
            }
        }

        // per-tile flush: one atomic per wave to its shard
        const unsigned n = wcount < SEG ? wcount : SEG;
        unsigned base = 0;
        if (lane == 0 && n) base = atomicAdd(&counters[wave * 16], n);
        base = (unsigned)__shfl((int)base, 0);
        for (unsigned i = lane; i < n; i += 64) {
            const unsigned v = wl[i];
            const unsigned slot = base + i;
            if (slot < C16) list[(size_t)wave * C16 + slot] = v;
            else exact_rescore(z, cbp, z2g, e2g, (int)(v >> 13), (int)(v & 8191u), best);
        }
    }
}

// ---------------- exact rescore of sharded candidate lists (wave per candidate) ----------------
__global__ __launch_bounds__(256) void k_rescore(
    const float* __restrict__ z, const float* __restrict__ cbp,
    const float* __restrict__ z2g, const float* __restrict__ e2g,
    const unsigned* __restrict__ list, const unsigned* __restrict__ counters, unsigned C16,
    unsigned long long* best)
{
    const unsigned wid = (blockIdx.x * blockDim.x + threadIdx.x) >> 6;
    const unsigned nw = (gridDim.x * blockDim.x) >> 6;
    const int lane = threadIdx.x & 63;
    #pragma unroll 1
    for (int s = 0; s < 16; ++s) {
        const unsigned n = min(counters[s * 16], C16);
        const unsigned* shard = list + (size_t)s * C16;
        for (unsigned i = wid; i < n; i += nw) {
            const unsigned v = shard[i];
            const unsigned row = v >> 13, col = v & 8191u;
            const float4 a = *reinterpret_cast<const float4*>(z + (size_t)row * DDIM + lane * 4);
            const float4 b = *reinterpret_cast<const float4*>(cbp + (size_t)col * DDIM + lane * 4);
            float sdot = fmaf(a.x, b.x, fmaf(a.y, b.y, fmaf(a.z, b.z, a.w * b.w)));
            #pragma unroll
            for (int off = 1; off < 64; off <<= 1) sdot += __shfl_xor(sdot, off);
            if (lane == 0) {
                const float de = z2g[row] + e2g[col] - 2.0f * sdot;
                const unsigned long long key =
                    ((unsigned long long)__float_as_uint(de) << 32) | col;
                atomicMin(&best[row], key);
            }
        }
    }
}

// ---------------- gather + z_st + loss + final scalars (ticket) ----------------
__global__ __launch_bounds__(1024) void k_gather(
    const float* __restrict__ z, const float* __restrict__ cbp,
    const unsigned long long* __restrict__ best,
    float* __restrict__ out, float* __restrict__ accum, unsigned* __restrict__ gctr)
{
    __shared__ float wsum[16];
    const int tid = threadIdx.x;
    const int row = blockIdx.x * 16 + (tid >> 6);
    const int lane = tid & 63;
    const unsigned k = (unsigned)(best[row] & 0xFFFFFFFFull);
    const float4 ze = *reinterpret_cast<const float4*>(z + (size_t)row * DDIM + lane * 4);
    const float4 cq = *reinterpret_cast<const float4*>(cbp + (size_t)k * DDIM + lane * 4);
    float4 zst;
    zst.x = ze.x + (cq.x - ze.x); zst.y = ze.y + (cq.y - ze.y);
    zst.z = ze.z + (cq.z - ze.z); zst.w = ze.w + (cq.w - ze.w);
    *reinterpret_cast<float4*>(out + (size_t)row * DDIM + lane * 4) = zst;
    const float dx = cq.x - ze.x, dy = cq.y - ze.y, dz = cq.z - ze.z, dw = cq.w - ze.w;
    float s = dx * dx + dy * dy + dz * dz + dw * dw;
    #pragma unroll
    for (int off = 32; off > 0; off >>= 1) s += __shfl_down(s, off);
    if (lane == 0) {
        wsum[tid >> 6] = s;
        out[(size_t)NROWS * DDIM + row] = (float)k;
    }
    __syncthreads();
    if (tid == 0) {
        float tot = 0.f;
        #pragma unroll
        for (int i = 0; i < 16; ++i) tot += wsum[i];
        atomicAdd(accum, tot);
        __threadfence();
        const unsigned t = atomicAdd(gctr, 1u);
        if (t == GATHER_BLOCKS - 1) {
            const float total = atomicAdd(accum, 0.0f);
            const float m = total / (float)(NROWS * DDIM);
            out[(size_t)NROWS * DDIM + NROWS + 0] = m;
            out[(size_t)NROWS * DDIM + NROWS + 1] = m;
        }
    }
}

extern "C" void kernel_launch(void* const* d_in, const int* in_sizes, int n_in,
                              void* d_out, int out_size, void* d_ws, size_t ws_size,
                              hipStream_t stream)
{
    const float* z  = (const float*)d_in[0];
    const float* cb = (const float*)d_in[1];
    float* out = (float*)d_out;

    // bf16 pre-tiled codebook lives in d_out's z_st region (4 MB of 16.8 MB),
    // consumed by k_screen and fully overwritten afterwards by k_gather.
    unsigned short* cb_t = (unsigned short*)d_out;        // 4 MB

    char* ws = (char*)d_ws;
    unsigned long long* best = (unsigned long long*)ws;   // 131072 B
    float* e2      = (float*)(ws + 131072);               // 32768 B
    float* z2      = (float*)(ws + 163840);               // 65536 B
    float* accum   = (float*)(ws + 229376);
    unsigned* gctr = (unsigned*)(ws + 229380);
    unsigned* counters = (unsigned*)(ws + 229440);        // 16 shard counters, 64B apart
    unsigned* list = (unsigned*)(ws + 230464);
    unsigned C16 = 0;
    if (ws_size > 230464 + 64) {
        size_t c = (ws_size - 230464) / 4 / 16;
        if (c > (1u << 19)) c = (1u << 19);
        C16 = (unsigned)c;
    }

    k_convert<<<128, 256, 0, stream>>>(cb, cb_t, e2, best, accum, counters, gctr);
    k_screen<<<256, 1024, 0, stream>>>(z, cb, cb_t, z2, e2, best, counters, list, C16);
    k_rescore<<<1024, 256, 0, stream>>>(z, cb, z2, e2, list, counters, C16, best);
    k_gather<<<GATHER_BLOCKS, 1024, 0, stream>>>(z, cb, best, out, accum, gctr);
}

// Round 18
// 208.947 us; speedup vs baseline: 1.3591x; 1.0159x over previous
//
#include <hip/hip_runtime.h>

#define NROWS 16384
#define KCODES 8192
#define DDIM 256
#define MARGIN 1.0f
#define SEG 192
#define NCT 16     // 512-col tiles (block sweeps all 8192 cols)
#define GATHER_BLOCKS (NROWS / 16)

typedef __attribute__((ext_vector_type(8))) short short8;
typedef __attribute__((ext_vector_type(4))) float f32x4;

// ---------------- helpers ----------------
__device__ inline unsigned short f2bf(float x) {
    unsigned u = __float_as_uint(x);
    return (unsigned short)((u + 0x7FFFu + ((u >> 16) & 1u)) >> 16);  // RNE
}

__device__ inline unsigned mbcnt64(unsigned long long m) {
    unsigned lo = __builtin_amdgcn_mbcnt_lo((unsigned)m, 0u);
    return __builtin_amdgcn_mbcnt_hi((unsigned)(m >> 32), lo);
}

__device__ inline void exact_rescore(const float* __restrict__ z, const float* __restrict__ cb,
                                     const float* __restrict__ z2g, const float* __restrict__ e2g,
                                     int grow, int gcol, unsigned long long* best) {
    const float4* av = reinterpret_cast<const float4*>(z + (size_t)grow * DDIM);
    const float4* bv = reinterpret_cast<const float4*>(cb + (size_t)gcol * DDIM);
    float dot = 0.f;
    #pragma unroll 8
    for (int j = 0; j < 64; ++j) {
        const float4 xa = av[j], xb = bv[j];
        dot = fmaf(xa.x, xb.x, fmaf(xa.y, xb.y, fmaf(xa.z, xb.z, fmaf(xa.w, xb.w, dot))));
    }
    const float de = z2g[grow] + e2g[gcol] - 2.0f * dot;
    const unsigned long long key =
        ((unsigned long long)__float_as_uint(de) << 32) | (unsigned)gcol;
    atomicMin(best + grow, key);
}

// ---------------- convert cb fp32 -> bf16 pre-tiled fragment layout + e2 + init ----------------
// chunk (g, kb2): 1 KB, slot s: row g*16 + (s&15), k = kb2*32 + (s>>4)*8 .. +8
__global__ __launch_bounds__(256) void k_convert(
    const float* __restrict__ cb, unsigned short* __restrict__ cb_t,
    float* __restrict__ e2,
    unsigned long long* best, float* accum, unsigned* counters, unsigned* gctr)
{
    const int tid = threadIdx.x;
    const int bx = blockIdx.x;
    if (bx < 64) {
        const int gid = bx * 256 + tid;
        best[gid] = 0xFFFFFFFFFFFFFFFFull;
    }
    if (bx == 0) {
        if (tid < 16) counters[tid * 16] = 0u;
        if (tid == 0) { accum[0] = 0.0f; gctr[0] = 0u; }
    }
    const int g = bx * 4 + (tid >> 6);       // 512 groups over 128 blocks
    const int lane = tid & 63;
    const int row = g * 16 + (lane & 15);
    const int ko = (lane >> 4) * 8;
    float ss = 0.f;
    #pragma unroll
    for (int kb2 = 0; kb2 < 8; ++kb2) {
        const float4* src = reinterpret_cast<const float4*>(cb + (size_t)row * DDIM + kb2 * 32 + ko);
        const float4 a = src[0], b = src[1];
        ss += a.x * a.x + a.y * a.y + a.z * a.z + a.w * a.w
            + b.x * b.x + b.y * b.y + b.z * b.z + b.w * b.w;
        short8 p;
        p[0] = (short)f2bf(a.x); p[1] = (short)f2bf(a.y); p[2] = (short)f2bf(a.z); p[3] = (short)f2bf(a.w);
        p[4] = (short)f2bf(b.x); p[5] = (short)f2bf(b.y); p[6] = (short)f2bf(b.z); p[7] = (short)f2bf(b.w);
        *reinterpret_cast<short8*>(cb_t + (((size_t)(g * 8 + kb2)) << 9) + lane * 8) = p;
    }
    ss += __shfl_xor(ss, 16);
    ss += __shfl_xor(ss, 32);
    if (lane < 16) e2[g * 16 + lane] = ss;
}

// ---------------- MFMA screen: A in LDS, B straight from L2/L3 to registers ----------------
// 64 rows x ALL 8192 cols per block; wave tile 32x64 (acc[2][4]).
// K-loop is BARRIER-FREE: per step each wave loads its 4 B fragments from cb_t
// (wave-uniform base + lane*16, 1KB coalesced, L2/L3-resident) + 2 A ds_reads + 8 MFMA.
// Epilogue per tile: 2 lgkm-only barriers -> block-tight running threshold -> ballot emit.
// LDS: A 32K @0 | rowmin[8][64] @32768 | thrbuf[64] @34816 | wl 16xSEG @35072
__global__ __launch_bounds__(1024, 4) void k_screen(
    const float* __restrict__ z, const float* __restrict__ cbp,
    const unsigned short* __restrict__ cb_t,
    float* z2g, const float* __restrict__ e2g,
    unsigned long long* __restrict__ best,
    unsigned* __restrict__ counters, unsigned* __restrict__ list, unsigned C16)
{
    __shared__ __align__(16) char smem[47360];
    char* ldsA = smem;
    float* rowmin = (float*)(smem + 32768);    // [8][64]
    float* thrbuf = (float*)(smem + 34816);    // [64] running block min (incl. current tile)
    unsigned* wl_all = (unsigned*)(smem + 35072);

    const int tid = threadIdx.x;
    const int lane = tid & 63;
    const int wave = tid >> 6;     // 0..15
    const int wm = wave & 1;       // 32-row half
    const int wn = wave >> 1;      // 0..7 col-64 group
    const int lhi = lane >> 4;
    const int llo = lane & 15;

    const int rt = blockIdx.x;     // 256 blocks, 64-row bands
    const int row0 = rt * 64;

    // ---- prologue ----
    // fused z-convert: fp32 band -> bf16 fragments straight into ldsA (2 slots/thread)
    {
        const int c = tid >> 5;                // chunk 0..31: gl = c>>3, kb2 = c&7
        const int gl = c >> 3, kb2 = c & 7;
        const int sp = (tid & 31) * 2;
        #pragma unroll
        for (int i = 0; i < 2; ++i) {
            const int s = sp + i;
            const int row = gl * 16 + (s & 15);
            const int k = kb2 * 32 + (s >> 4) * 8;
            const float4* src = reinterpret_cast<const float4*>(z + (size_t)(row0 + row) * DDIM + k);
            const float4 a = src[0], b = src[1];
            short8 p;
            p[0] = (short)f2bf(a.x); p[1] = (short)f2bf(a.y); p[2] = (short)f2bf(a.z); p[3] = (short)f2bf(a.w);
            p[4] = (short)f2bf(b.x); p[5] = (short)f2bf(b.y); p[6] = (short)f2bf(b.z); p[7] = (short)f2bf(b.w);
            *reinterpret_cast<short8*>(ldsA + c * 1024 + s * 16) = p;
        }
    }

    // z2 for own band (additive per-row constant used by rescore keys)
    #pragma unroll
    for (int rr = 0; rr < 4; ++rr) {
        const int row = wave * 4 + rr;
        const float4 v = *reinterpret_cast<const float4*>(z + (size_t)(row0 + row) * DDIM + lane * 4);
        float s = v.x * v.x + v.y * v.y + v.z * v.z + v.w * v.w;
        #pragma unroll
        for (int off = 1; off < 64; off <<= 1) s += __shfl_xor(s, off);
        if (lane == 0) z2g[row0 + row] = s;
    }

    if (tid < 64) thrbuf[tid] = 3.0e38f;
    __syncthreads();   // ldsA writes + z2 complete

    unsigned* wl = wl_all + wave * SEG;

    #pragma unroll 1
    for (int ci = 0; ci < NCT; ++ci) {
        f32x4 acc[2][4];
        #pragma unroll
        for (int i = 0; i < 2; ++i)
            #pragma unroll
            for (int j = 0; j < 4; ++j) { acc[i][j][0]=0.f; acc[i][j][1]=0.f; acc[i][j][2]=0.f; acc[i][j][3]=0.f; }

        // ---- K loop: 8 steps of K=32, barrier-free, B from global (L2/L3) ----
        const char* bbase = (const char*)cb_t + (((size_t)((ci * 32 + wn * 4)) * 8) << 10) + lane * 16;
        #pragma unroll
        for (int kb2 = 0; kb2 < 8; ++kb2) {
            short8 bfr[4];
            #pragma unroll
            for (int fn = 0; fn < 4; ++fn)
                bfr[fn] = *reinterpret_cast<const short8*>(bbase + fn * 8192 + kb2 * 1024);
            #pragma unroll
            for (int fm = 0; fm < 2; ++fm) {
                const short8 af = *reinterpret_cast<const short8*>(
                    ldsA + (((wm * 2 + fm) * 8) + kb2) * 1024 + lane * 16);
                #pragma unroll
                for (int fn = 0; fn < 4; ++fn)
                    acc[fm][fn] = __builtin_amdgcn_mfma_f32_16x16x32_bf16(af, bfr[fn], acc[fm][fn], 0, 0, 0);
            }
        }

        // ---- epilogue: block-tight threshold (2 lgkm-only barriers) ----
        const int c0 = ci * 512 + wn * 64 + llo;
        float e2c[4];
        #pragma unroll
        for (int fn = 0; fn < 4; ++fn) e2c[fn] = e2g[c0 + fn * 16];

        // phase A: per-wave per-row min over this tile's 64-col slice
        #pragma unroll
        for (int fm = 0; fm < 2; ++fm) {
            #pragma unroll
            for (int rg = 0; rg < 4; ++rg) {
                const int rl = wm * 32 + fm * 16 + lhi * 4 + rg;
                float d[4];
                #pragma unroll
                for (int fn = 0; fn < 4; ++fn) d[fn] = fmaf(-2.0f, acc[fm][fn][rg], e2c[fn]);
                float m = fminf(fminf(d[0], d[1]), fminf(d[2], d[3]));
                #pragma unroll
                for (int off = 1; off < 16; off <<= 1) m = fminf(m, __shfl_xor(m, off));
                if (llo == 0) rowmin[wn * 64 + rl] = m;
            }
        }
        asm volatile("s_waitcnt lgkmcnt(0)" ::: "memory");
        __builtin_amdgcn_s_barrier();
        __builtin_amdgcn_sched_barrier(0);

        // merge: running block min now INCLUDES the current tile
        if (tid < 64) {
            float a = rowmin[tid];
            #pragma unroll
            for (int q = 1; q < 8; ++q) a = fminf(a, rowmin[q * 64 + tid]);
            thrbuf[tid] = fminf(thrbuf[tid], a);
        }
        asm volatile("s_waitcnt lgkmcnt(0)" ::: "memory");
        __builtin_amdgcn_s_barrier();
        __builtin_amdgcn_sched_barrier(0);

        // phase B: emit vs tight threshold (recompute d from acc)
        unsigned wcount = 0;
        #pragma unroll
        for (int fm = 0; fm < 2; ++fm) {
            #pragma unroll
            for (int rg = 0; rg < 4; ++rg) {
                const int rl = wm * 32 + fm * 16 + lhi * 4 + rg;
                const float thr = thrbuf[rl] + MARGIN;
                float d[4];
                #pragma unroll
                for (int fn = 0; fn < 4; ++fn) d[fn] = fmaf(-2.0f, acc[fm][fn][rg], e2c[fn]);
                const bool hit = (d[0] <= thr) | (d[1] <= thr) | (d[2] <= thr) | (d[3] <= thr);
                if (__any(hit)) {
                    const int grow = row0 + rl;
                    #pragma unroll
                    for (int fn = 0; fn < 4; ++fn) {
                        const bool p = d[fn] <= thr;
                        const unsigned long long mask = __ballot(p);
                        if (mask) {
                            if (p) {
                                const unsigned pos = wcount + mbcnt64(mask);
                                const unsigned v = ((unsigned)grow << 13) | (unsigned)(c0 + fn * 16);
                                if (pos < SEG) wl[pos] = v;
                                else exact_rescore(z, cbp, z2g, e2g, grow, c0 + fn * 16, best);
                            }
                            wcount += (unsigned)__popcll(mask);
                        }
                    }
                }
            }
        }

        // per-tile flush: one atomic per wave to its shard
        const unsigned n = wcount < SEG ? wcount : SEG;
        unsigned base = 0;
        if (lane == 0 && n) base = atomicAdd(&counters[wave * 16], n);
        base = (unsigned)__shfl((int)base, 0);
        for (unsigned i = lane; i < n; i += 64) {
            const unsigned v = wl[i];
            const unsigned slot = base + i;
            if (slot < C16) list[(size_t)wave * C16 + slot] = v;
            else exact_rescore(z, cbp, z2g, e2g, (int)(v >> 13), (int)(v & 8191u), best);
        }
    }
}

// ---------------- exact rescore of sharded candidate lists (wave per candidate) ----------------
__global__ __launch_bounds__(256) void k_rescore(
    const float* __restrict__ z, const float* __restrict__ cbp,
    const float* __restrict__ z2g, const float* __restrict__ e2g,
    const unsigned* __restrict__ list, const unsigned* __restrict__ counters, unsigned C16,
    unsigned long long* best)
{
    const unsigned wid = (blockIdx.x * blockDim.x + threadIdx.x) >> 6;
    const unsigned nw = (gridDim.x * blockDim.x) >> 6;
    const int lane = threadIdx.x & 63;
    #pragma unroll 1
    for (int s = 0; s < 16; ++s) {
        const unsigned n = min(counters[s * 16], C16);
        const unsigned* shard = list + (size_t)s * C16;
        for (unsigned i = wid; i < n; i += nw) {
            const unsigned v = shard[i];
            const unsigned row = v >> 13, col = v & 8191u;
            const float4 a = *reinterpret_cast<const float4*>(z + (size_t)row * DDIM + lane * 4);
            const float4 b = *reinterpret_cast<const float4*>(cbp + (size_t)col * DDIM + lane * 4);
            float sdot = fmaf(a.x, b.x, fmaf(a.y, b.y, fmaf(a.z, b.z, a.w * b.w)));
            #pragma unroll
            for (int off = 1; off < 64; off <<= 1) sdot += __shfl_xor(sdot, off);
            if (lane == 0) {
                const float de = z2g[row] + e2g[col] - 2.0f * sdot;
                const unsigned long long key =
                    ((unsigned long long)__float_as_uint(de) << 32) | col;
                atomicMin(&best[row], key);
            }
        }
    }
}

// ---------------- gather + z_st + loss + final scalars (ticket) ----------------
__global__ __launch_bounds__(1024) void k_gather(
    const float* __restrict__ z, const float* __restrict__ cbp,
    const unsigned long long* __restrict__ best,
    float* __restrict__ out, float* __restrict__ accum, unsigned* __restrict__ gctr)
{
    __shared__ float wsum[16];
    const int tid = threadIdx.x;
    const int row = blockIdx.x * 16 + (tid >> 6);
    const int lane = tid & 63;
    const unsigned k = (unsigned)(best[row] & 0xFFFFFFFFull);
    const float4 ze = *reinterpret_cast<const float4*>(z + (size_t)row * DDIM + lane * 4);
    const float4 cq = *reinterpret_cast<const float4*>(cbp + (size_t)k * DDIM + lane * 4);
    float4 zst;
    zst.x = ze.x + (cq.x - ze.x); zst.y = ze.y + (cq.y - ze.y);
    zst.z = ze.z + (cq.z - ze.z); zst.w = ze.w + (cq.w - ze.w);
    *reinterpret_cast<float4*>(out + (size_t)row * DDIM + lane * 4) = zst;
    const float dx = cq.x - ze.x, dy = cq.y - ze.y, dz = cq.z - ze.z, dw = cq.w - ze.w;
    float s = dx * dx + dy * dy + dz * dz + dw * dw;
    #pragma unroll
    for (int off = 32; off > 0; off >>= 1) s += __shfl_down(s, off);
    if (lane == 0) {
        wsum[tid >> 6] = s;
        out[(size_t)NROWS * DDIM + row] = (float)k;
    }
    __syncthreads();
    if (tid == 0) {
        float tot = 0.f;
        #pragma unroll
        for (int i = 0; i < 16; ++i) tot += wsum[i];
        atomicAdd(accum, tot);
        __threadfence();
        const unsigned t = atomicAdd(gctr, 1u);
        if (t == GATHER_BLOCKS - 1) {
            const float total = atomicAdd(accum, 0.0f);
            const float m = total / (float)(NROWS * DDIM);
            out[(size_t)NROWS * DDIM + NROWS + 0] = m;
            out[(size_t)NROWS * DDIM + NROWS + 1] = m;
        }
    }
}

extern "C" void kernel_launch(void* const* d_in, const int* in_sizes, int n_in,
                              void* d_out, int out_size, void* d_ws, size_t ws_size,
                              hipStream_t stream)
{
    const float* z  = (const float*)d_in[0];
    const float* cb = (const float*)d_in[1];
    float* out = (float*)d_out;

    // bf16 pre-tiled codebook lives in d_out's z_st region (4 MB of 16.8 MB),
    // consumed by k_screen and fully overwritten afterwards by k_gather.
    unsigned short* cb_t = (unsigned short*)d_out;        // 4 MB

    char* ws = (char*)d_ws;
    unsigned long long* best = (unsigned long long*)ws;   // 131072 B
    float* e2      = (float*)(ws + 131072);               // 32768 B
    float* z2      = (float*)(ws + 163840);               // 65536 B
    float* accum   = (float*)(ws + 229376);
    unsigned* gctr = (unsigned*)(ws + 229380);
    unsigned* counters = (unsigned*)(ws + 229440);        // 16 shard counters, 64B apart
    unsigned* list = (unsigned*)(ws + 230464);
    unsigned C16 = 0;
    if (ws_size > 230464 + 64) {
        size_t c = (ws_size - 230464) / 4 / 16;
        if (c > (1u << 19)) c = (1u << 19);
        C16 = (unsigned)c;
    }

    k_convert<<<128, 256, 0, stream>>>(cb, cb_t, e2, best, accum, counters, gctr);
    k_screen<<<256, 1024, 0, stream>>>(z, cb, cb_t, z2, e2, best, counters, list, C16);
    k_rescore<<<1024, 256, 0, stream>>>(z, cb, z2, e2, list, counters, C16, best);
    k_gather<<<GATHER_BLOCKS, 1024, 0, stream>>>(z, cb, best, out, accum, gctr);
}